// Round 3
// baseline (58.553 us; speedup 1.0000x reference)
//
#include <hip/hip_runtime.h>
#include <hip/hip_bf16.h>

// Capsule routing-by-agreement: X [B, N=64, D=64] fp32 -> v [B, 64] fp32.
// One WAVE per batch element-chunk (8 elements), entire 16KB tile register-
// resident, register double-buffered across elements so ~16KB of loads are
// always in flight during compute. Zero LDS, zero barriers.
//   lane l (h=l>>4, g=l&15) holds X[4i+h][4g..4g+3], i=0..15  (16 x float4).

#define ELEMS 8   // batch elements per wave

__device__ __forceinline__ void issue_load(float4 (&buf)[16],
                                           const float* __restrict__ Xb, int l) {
    #pragma unroll
    for (int i = 0; i < 16; ++i)
        buf[i] = *reinterpret_cast<const float4*>(Xb + i * 256 + 4 * l);
}

__device__ __forceinline__ void process(const float4 (&data)[16],
                                        float* __restrict__ outp, int l) {
    const int g = l & 15;
    float blog[16];
    #pragma unroll
    for (int i = 0; i < 16; ++i) blog[i] = 0.0f;

    float c[16];
    float4 v4 = make_float4(0.f, 0.f, 0.f, 0.f);

    #pragma unroll
    for (int it = 0; it < 3; ++it) {
        float4 s4;
        if (it == 0) {
            // uniform c = 1/64
            s4 = make_float4(0.f, 0.f, 0.f, 0.f);
            #pragma unroll
            for (int i = 0; i < 16; ++i) {
                s4.x += data[i].x; s4.y += data[i].y;
                s4.z += data[i].z; s4.w += data[i].w;
            }
            s4.x *= 0.015625f; s4.y *= 0.015625f;
            s4.z *= 0.015625f; s4.w *= 0.015625f;
        } else {
            // softmax over 64 rows; this lane owns rows {4i+h}
            float m = blog[0];
            #pragma unroll
            for (int i = 1; i < 16; ++i) m = fmaxf(m, blog[i]);
            m = fmaxf(m, __shfl_xor(m, 16));
            m = fmaxf(m, __shfl_xor(m, 32));
            float sum = 0.0f;
            #pragma unroll
            for (int i = 0; i < 16; ++i) { c[i] = __expf(blog[i] - m); sum += c[i]; }
            sum += __shfl_xor(sum, 16);
            sum += __shfl_xor(sum, 32);
            const float r = 1.0f / sum;
            #pragma unroll
            for (int i = 0; i < 16; ++i) c[i] *= r;

            s4 = make_float4(0.f, 0.f, 0.f, 0.f);
            #pragma unroll
            for (int i = 0; i < 16; ++i) {
                s4.x = fmaf(c[i], data[i].x, s4.x);
                s4.y = fmaf(c[i], data[i].y, s4.y);
                s4.z = fmaf(c[i], data[i].z, s4.z);
                s4.w = fmaf(c[i], data[i].w, s4.w);
            }
        }
        // reduce partial s over the 4 h-groups
        #pragma unroll
        for (int off = 16; off <= 32; off <<= 1) {
            s4.x += __shfl_xor(s4.x, off);
            s4.y += __shfl_xor(s4.y, off);
            s4.z += __shfl_xor(s4.z, off);
            s4.w += __shfl_xor(s4.w, off);
        }
        // squash
        float n2 = s4.x * s4.x + s4.y * s4.y + s4.z * s4.z + s4.w * s4.w;
        #pragma unroll
        for (int off = 1; off <= 8; off <<= 1) n2 += __shfl_xor(n2, off);
        const float norm = sqrtf(n2);
        const float scale = n2 / (1.0f + n2) / (norm + 1e-8f);
        v4.x = scale * s4.x; v4.y = scale * s4.y;
        v4.z = scale * s4.z; v4.w = scale * s4.w;

        if (it < 2) {
            // agreement: b[4i+h] += X[row] . v   (v lane-local: same cols)
            #pragma unroll
            for (int i = 0; i < 16; ++i) {
                float a = data[i].x * v4.x + data[i].y * v4.y
                        + data[i].z * v4.z + data[i].w * v4.w;
                #pragma unroll
                for (int off = 1; off <= 8; off <<= 1) a += __shfl_xor(a, off);
                blog[i] += a;
            }
        }
    }

    if (l < 16)
        *reinterpret_cast<float4*>(outp + 4 * g) = v4;
}

__global__ __launch_bounds__(256, 2)
void routing_kernel(const float* __restrict__ X, float* __restrict__ out, int B) {
    const int wid = (blockIdx.x << 2) + (threadIdx.x >> 6);
    const int l = threadIdx.x & 63;
    const int base = wid * ELEMS;
    if (base >= B) return;

    float4 bufA[16], bufB[16];

    // prologue: element `base` into A
    issue_load(bufA, X + (size_t)base * 4096, l);

    #pragma unroll 1
    for (int e = 0; e < ELEMS; e += 2) {
        const int elem = base + e;
        const bool has1 = (elem + 1 < B);
        const bool has2 = has1 && (e + 2 < ELEMS) && (elem + 2 < B);

        if (has1) issue_load(bufB, X + (size_t)(elem + 1) * 4096, l);
        process(bufA, out + (size_t)elem * 64, l);
        if (has2) issue_load(bufA, X + (size_t)(elem + 2) * 4096, l);
        if (has1) process(bufB, out + (size_t)(elem + 1) * 64, l);
        if (elem + 2 >= B) break;
    }
}

extern "C" void kernel_launch(void* const* d_in, const int* in_sizes, int n_in,
                              void* d_out, int out_size, void* d_ws, size_t ws_size,
                              hipStream_t stream) {
    const float* X = (const float*)d_in[0];
    float* out = (float*)d_out;
    const int B = in_sizes[0] / 4096;                 // 16384
    const int waves = (B + ELEMS - 1) / ELEMS;        // 2048
    const int blocks = (waves + 3) / 4;               // 512 (4 waves/block)
    routing_kernel<<<blocks, 256, 0, stream>>>(X, out, B);
}